// Round 7
// baseline (151.769 us; speedup 1.0000x reference)
//
#include <hip/hip_runtime.h>

#define NN 20
#define NP 125          // 5^3 window
#define NV (NN*NN*NN)   // 8000

// ---------------------------------------------------------------------------
// pre: single kernel replacing prep+qkv2 (saves a launch; rel-rows run in
// parallel with the voxel projections).
// blocks 0..499  : 16 voxels each ->
//     Q[v]  = SE[v]@Wq + bq
//     Km[v] = SE[v]@Wk[96:]
//     VW[v] = SE[v]@Wvo, with Wvo = Wv[96:]@Wo computed redundantly
//             per-block into LDS (removes the prep->qkv dependency).
// blocks 500..531: 4 relpos rows each ->
//     k_rel[p] = bk + relpos_flat[p]@Wk[0:96]
//     vrelW[p] = (bv + relpos_flat[p]@Wv[0:96])@Wo
// ---------------------------------------------------------------------------
__global__ __launch_bounds__(256) void pre(
        const float* __restrict__ SE, const float* __restrict__ rpw,
        const float* __restrict__ Wq, const float* __restrict__ bq,
        const float* __restrict__ Wk, const float* __restrict__ bk,
        const float* __restrict__ Wv, const float* __restrict__ bv,
        const float* __restrict__ Wo,
        float* __restrict__ Q, float* __restrict__ Km, float* __restrict__ VW,
        float* __restrict__ k_rel, float* __restrict__ vrelW) {
    const int t = threadIdx.x;
    const int lane = t & 63, w = t >> 6;   // 4 waves

    if (blockIdx.x < 500) {
        __shared__ float se_s[16][65];
        __shared__ float wvo_s[64 * 65];
        const int vbase = blockIdx.x * 16;
        {   // stage 16x64 floats = 256 float4, 1 per thread
            const float4 a = ((const float4*)(SE + vbase * 64))[t];
            const int r0 = t >> 4, c0 = (t & 15) * 4;
            se_s[r0][c0 + 0] = a.x; se_s[r0][c0 + 1] = a.y;
            se_s[r0][c0 + 2] = a.z; se_s[r0][c0 + 3] = a.w;
        }
        // Wvo = Wv[96:]@Wo, 16 d-rows per wave
        float acc[16];
#pragma unroll
        for (int k = 0; k < 16; ++k) acc[k] = 0.f;
#pragma unroll 4
        for (int e = 0; e < 64; ++e) {
            const float wo = Wo[e * 64 + lane];
#pragma unroll
            for (int k = 0; k < 16; ++k)
                acc[k] = fmaf(Wv[(96 + w * 16 + k) * 64 + e], wo, acc[k]);
        }
#pragma unroll
        for (int k = 0; k < 16; ++k)
            wvo_s[(w * 16 + k) * 65 + lane] = acc[k];
        __syncthreads();

        // qkv: 4 voxels per wave
        float aq[4], ak[4], av[4];
#pragma unroll
        for (int j = 0; j < 4; ++j) { aq[j] = bq[lane]; ak[j] = 0.f; av[j] = 0.f; }
#pragma unroll 8
        for (int d = 0; d < 64; ++d) {
            const float wq = Wq[d * 64 + lane];
            const float wk = Wk[(96 + d) * 64 + lane];
            const float wv = wvo_s[d * 65 + lane];
#pragma unroll
            for (int j = 0; j < 4; ++j) {
                const float s = se_s[w * 4 + j][d];   // uniform addr broadcast
                aq[j] = fmaf(s, wq, aq[j]);
                ak[j] = fmaf(s, wk, ak[j]);
                av[j] = fmaf(s, wv, av[j]);
            }
        }
#pragma unroll
        for (int j = 0; j < 4; ++j) {
            const int v = vbase + w * 4 + j;
            Q[v * 64 + lane]  = aq[j];
            Km[v * 64 + lane] = ak[j];
            VW[v * 64 + lane] = av[j];
        }
    } else {
        __shared__ float vt[4][65];
        const int p = (blockIdx.x - 500) * 4 + w;   // one p-row per wave
        const int pc = (p < NP) ? p : (NP - 1);
        const int d3 = pc / 25, d4 = (pc / 5) % 5, d5 = pc % 5;
        float ak = bk[lane], av = bv[lane];
#pragma unroll
        for (int tt = 0; tt < 96; ++tt) {
            const int blk = tt >> 5, off = tt & 31;
            const int row = (blk == 0) ? d3 : (blk == 1) ? d4 : d5;
            const float r = rpw[row * 32 + off];
            ak = fmaf(r, Wk[tt * 64 + lane], ak);
            av = fmaf(r, Wv[tt * 64 + lane], av);
        }
        vt[w][lane] = av;
        __syncthreads();
        float o = 0.f;
#pragma unroll 4
        for (int e = 0; e < 64; ++e)
            o = fmaf(vt[w][e], Wo[e * 64 + lane], o);
        if (p < NP) {
            k_rel[p * 64 + lane] = ak;
            vrelW[p * 64 + lane] = o;
        }
    }
}

// ---------------------------------------------------------------------------
// attn5: block = 512 threads (8 waves) = 2x2x2 voxel tile; grid 1000.
// XCD-AWARE CUBIC CHUNKING (proven r6: FETCH 183MB->4.8MB): hw round-robin
// puts bx%8 on XCD bx%8; chunk (bx&7) = cubic 5x5x5 tile region -> each XCD's
// Km/VW footprint ~1.4MB, L2-resident.
// Km union staged in LDS u[216][65] (stride 65 -> near-conflict-free);
// OOB rows zero-filled (reference zero padding). k_rel/vrelW/VW rows read
// DIRECT from global: per-p per-wave reads are coalesced 256B rows, L1/L2-hot.
// REFERENCE QUIRKS: gather coord = (x+e4-2, y+e3-2, z+e5-2) [x/y digit swap];
// mask coord = (x+e3-2, y+e4-2, z+e5-2) in [1,19]^3; masked score exactly 0.
// ---------------------------------------------------------------------------
__global__ __launch_bounds__(512, 4) void attn5(
        const float* __restrict__ Q, const float* __restrict__ Km,
        const float* __restrict__ VW,
        const float* __restrict__ k_rel, const float* __restrict__ vrelW,
        const float* __restrict__ bo,
        float* __restrict__ out) {
    __shared__ float u[216 * 65];
    __shared__ float sc_s[8][128];

    const int tid  = threadIdx.x;
    const int lane = tid & 63;
    const int w    = tid >> 6;

    // ---- XCD-aware cubic chunking ----
    const int chunk = blockIdx.x & 7;          // hw XCD (round-robin)
    const int idx   = blockIdx.x >> 3;         // 0..124 within chunk
    const int cx = chunk >> 2, cy = (chunk >> 1) & 1, cz = chunk & 1;
    const int TX = cx * 5 + idx / 25;
    const int TY = cy * 5 + (idx / 5) % 5;
    const int TZ = cz * 5 + idx % 5;

    const int wx = w >> 2, wy = (w >> 1) & 1, wz = w & 1;
    const int x = TX * 2 + wx, y = TY * 2 + wy, z = TZ * 2 + wz;
    const int v = (x * NN + y) * NN + z;

    // ---- stage Km union (216 rows, zero-fill OOB) ----
    for (int i = tid; i < 216 * 16; i += 512) {
        const int row = i >> 4, ch = i & 15;
        const int ux = row / 36, uy = (row / 6) % 6, uz = row % 6;
        const int gX = TX * 2 - 2 + ux;
        const int gY = TY * 2 - 2 + uy;
        const int gZ = TZ * 2 - 2 + uz;
        float4 val = make_float4(0.f, 0.f, 0.f, 0.f);
        if ((unsigned)gX <= 19u && (unsigned)gY <= 19u && (unsigned)gZ <= 19u)
            val = ((const float4*)Km)[((gX * NN + gY) * NN + gZ) * 16 + ch];
        const int b = row * 65 + ch * 4;
        u[b] = val.x; u[b + 1] = val.y; u[b + 2] = val.z; u[b + 3] = val.w;
    }

    const float q = Q[v * 64 + lane];
    const int p0 = lane;
    const int p1 = lane + 64;
    const int p1c = (p1 < NP) ? p1 : (NP - 1);

    // geometry (digit-swap quirk)
    int e3 = p0 / 25, e4 = (p0 / 5) % 5, e5 = p0 % 5;
    const int row0 = 36 * (wx + e4) + 6 * (wy + e3) + (wz + e5);
    const bool mv0 = ((unsigned)(x + e3 - 3) <= 18u) &&
                     ((unsigned)(y + e4 - 3) <= 18u) &&
                     ((unsigned)(z + e5 - 3) <= 18u);
    e3 = p1c / 25; e4 = (p1c / 5) % 5; e5 = p1c % 5;
    const int row1 = 36 * (wx + e4) + 6 * (wy + e3) + (wz + e5);
    const bool mv1 = (p1 < NP) &&
                     ((unsigned)(x + e3 - 3) <= 18u) &&
                     ((unsigned)(y + e4 - 3) <= 18u) &&
                     ((unsigned)(z + e5 - 3) <= 18u);

    const float4* __restrict__ kr0 = (const float4*)(k_rel + p0 * 64);
    const float4* __restrict__ kr1 = (const float4*)(k_rel + p1c * 64);

    __syncthreads();   // Km union staged

    // ---- logits: Km from LDS + k_rel direct (L1-hot) ----
    float a0 = 0.f, a1 = 0.f;
#pragma unroll
    for (int i = 0; i < 16; ++i) {
        const float qa = __shfl(q, 4 * i + 0);
        const float qb = __shfl(q, 4 * i + 1);
        const float qc = __shfl(q, 4 * i + 2);
        const float qd = __shfl(q, 4 * i + 3);
        const float4 r0 = kr0[i], r1 = kr1[i];
        const int b0 = row0 * 65 + 4 * i;
        const int b1 = row1 * 65 + 4 * i;
        a0 = fmaf(u[b0] + r0.x, qa, a0);
        a0 = fmaf(u[b0 + 1] + r0.y, qb, a0);
        a0 = fmaf(u[b0 + 2] + r0.z, qc, a0);
        a0 = fmaf(u[b0 + 3] + r0.w, qd, a0);
        a1 = fmaf(u[b1] + r1.x, qa, a1);
        a1 = fmaf(u[b1 + 1] + r1.y, qb, a1);
        a1 = fmaf(u[b1 + 2] + r1.z, qc, a1);
        a1 = fmaf(u[b1 + 3] + r1.w, qd, a1);
    }
    const float l0 = mv0 ? a0 : -1e9f;
    const float l1 = mv1 ? a1 : -1e9f;

    // ---- softmax over 125 ----
    float m = fmaxf(l0, l1);
#pragma unroll
    for (int d = 1; d < 64; d <<= 1) m = fmaxf(m, __shfl_xor(m, d));
    const float e0 = __expf(l0 - m);
    const float e1 = __expf(l1 - m);
    float ssum = e0 + e1;
#pragma unroll
    for (int d = 1; d < 64; d <<= 1) ssum += __shfl_xor(ssum, d);
    const float inv = 1.f / ssum;
    sc_s[w][p0] = e0 * inv;
    sc_s[w][p1] = e1 * inv;   // p1 up to 127; clamped lanes store exact 0
    __syncthreads();          // scores visible to whole wave's reads

    // ---- weighted sum: lane = channel; VW rows DIRECT (coalesced, L2-hot) --
    bool xin[5], yin[5], zin[5];
#pragma unroll
    for (int o = 0; o < 5; ++o) {
        xin[o] = ((unsigned)(x + o - 2) <= 19u);
        yin[o] = ((unsigned)(y + o - 2) <= 19u);
        zin[o] = ((unsigned)(z + o - 2) <= 19u);
    }
    float A0 = 0.f, A1 = 0.f, A2 = 0.f, A3 = 0.f, A4 = 0.f;
    const float* __restrict__ vr = vrelW + lane;
    const float* __restrict__ vwl = VW + lane;
#pragma unroll 5
    for (int g = 0; g < 25; ++g) {
        const int ge3 = g / 5, ge4 = g % 5;
        const int nbb = v + (ge4 - 2) * 400 + (ge3 - 2) * 20 - 2;
        const bool xy = xin[ge4] && yin[ge3];
        const int pb = g * 5;
        {
            const float vm = (xy && zin[0]) ? vwl[(nbb + 0) * 64] : 0.f;
            A0 = fmaf(sc_s[w][pb + 0], vr[(pb + 0) * 64] + vm, A0);
        }
        {
            const float vm = (xy && zin[1]) ? vwl[(nbb + 1) * 64] : 0.f;
            A1 = fmaf(sc_s[w][pb + 1], vr[(pb + 1) * 64] + vm, A1);
        }
        {
            const float vm = (xy && zin[2]) ? vwl[(nbb + 2) * 64] : 0.f;
            A2 = fmaf(sc_s[w][pb + 2], vr[(pb + 2) * 64] + vm, A2);
        }
        {
            const float vm = (xy && zin[3]) ? vwl[(nbb + 3) * 64] : 0.f;
            A3 = fmaf(sc_s[w][pb + 3], vr[(pb + 3) * 64] + vm, A3);
        }
        {
            const float vm = (xy && zin[4]) ? vwl[(nbb + 4) * 64] : 0.f;
            A4 = fmaf(sc_s[w][pb + 4], vr[(pb + 4) * 64] + vm, A4);
        }
    }
    const float rw = ((A0 + A1) + (A2 + A3)) + A4;
    out[v * 64 + lane] = rw + bo[lane];
}

// ---------------------------------------------------------------------------
extern "C" void kernel_launch(void* const* d_in, const int* in_sizes, int n_in,
                              void* d_out, int out_size, void* d_ws, size_t ws_size,
                              hipStream_t stream) {
    const float* SE  = (const float*)d_in[0];
    const float* rpw = (const float*)d_in[1];
    const float* Wq  = (const float*)d_in[2];
    const float* bq  = (const float*)d_in[3];
    const float* Wk  = (const float*)d_in[4];
    const float* bk  = (const float*)d_in[5];
    const float* Wv  = (const float*)d_in[6];
    const float* bv  = (const float*)d_in[7];
    const float* Wo  = (const float*)d_in[8];
    const float* bo  = (const float*)d_in[9];
    float* out = (float*)d_out;

    float* ws    = (float*)d_ws;
    float* Q     = ws;                 // 8000*64
    float* Km    = ws + 512000;        // 8000*64
    float* VW    = ws + 1024000;       // 8000*64
    float* k_rel = ws + 1536000;       // 125*64
    float* vrelW = ws + 1544000;       // 125*64

    pre<<<532, 256, 0, stream>>>(SE, rpw, Wq, bq, Wk, bk, Wv, bv, Wo,
                                 Q, Km, VW, k_rel, vrelW);
    attn5<<<1000, 512, 0, stream>>>(Q, Km, VW, k_rel, vrelW, bo, out);
}

// Round 8
// 148.708 us; speedup vs baseline: 1.0206x; 1.0206x over previous
//
#include <hip/hip_runtime.h>

#define NN 20
#define NP 125          // 5^3 window
#define NV (NN*NN*NN)   // 8000

// ---------------------------------------------------------------------------
// prep: blocks 0..124  -> k_rel[p][c]  = bk + relpos_flat[p] @ Wk[0:96]
//                         vrelW[p][c]  = (bv + relpos_flat[p] @ Wv[0:96]) @ Wo
//       blocks 125..188 -> Wvo[d][c]   = Wv[96+d][:] @ Wo     (64x64)
// ---------------------------------------------------------------------------
__global__ __launch_bounds__(64) void prep(
        const float* __restrict__ rpw,
        const float* __restrict__ Wk, const float* __restrict__ bk,
        const float* __restrict__ Wv, const float* __restrict__ bv,
        const float* __restrict__ Wo,
        float* __restrict__ k_rel, float* __restrict__ vrelW,
        float* __restrict__ Wvo) {
    const int c = threadIdx.x;
    if (blockIdx.x < NP) {
        const int p = blockIdx.x;
        const int d3 = p / 25, d4 = (p / 5) % 5, d5 = p % 5;
        __shared__ float vtmp[64];
        float ak = bk[c], av = bv[c];
#pragma unroll
        for (int t = 0; t < 96; ++t) {
            const int blk = t >> 5, off = t & 31;
            const int row = (blk == 0) ? d3 : (blk == 1) ? d4 : d5;
            const float r = rpw[row * 32 + off];
            ak = fmaf(r, Wk[t * 64 + c], ak);
            av = fmaf(r, Wv[t * 64 + c], av);
        }
        k_rel[p * 64 + c] = ak;
        vtmp[c] = av;
        __syncthreads();
        float o = 0.f;
#pragma unroll 8
        for (int e = 0; e < 64; ++e)
            o = fmaf(vtmp[e], Wo[e * 64 + c], o);
        vrelW[p * 64 + c] = o;
    } else {
        const int d = blockIdx.x - NP;
        float acc = 0.f;
#pragma unroll 8
        for (int e = 0; e < 64; ++e)
            acc = fmaf(Wv[(96 + d) * 64 + e], Wo[e * 64 + c], acc);
        Wvo[d * 64 + c] = acc;
    }
}

// ---------------------------------------------------------------------------
// qkv2: Q = SE@Wq + bq ; Km = SE@Wk[96:] ; VW = SE@Wvo
// 250 blocks x 256 threads, 32 voxels/block (8 per wave).
// ---------------------------------------------------------------------------
__global__ __launch_bounds__(256) void qkv2(
        const float* __restrict__ SE,
        const float* __restrict__ Wq, const float* __restrict__ bq,
        const float* __restrict__ Wk, const float* __restrict__ Wvo,
        float* __restrict__ Q, float* __restrict__ Km, float* __restrict__ VW) {
    __shared__ float se_s[32][65];
    const int t = threadIdx.x;
    const int vbase = blockIdx.x * 32;
    {   // stage 32x64 floats = 512 float4, 2 per thread
        const float4* __restrict__ src = (const float4*)(SE + vbase * 64);
        const float4 a = src[t];
        const float4 b = src[t + 256];
        const int r0 = t >> 4,        c0 = (t & 15) * 4;
        const int r1 = (t + 256) >> 4;
        se_s[r0][c0 + 0] = a.x; se_s[r0][c0 + 1] = a.y;
        se_s[r0][c0 + 2] = a.z; se_s[r0][c0 + 3] = a.w;
        se_s[r1][c0 + 0] = b.x; se_s[r1][c0 + 1] = b.y;
        se_s[r1][c0 + 2] = b.z; se_s[r1][c0 + 3] = b.w;
    }
    __syncthreads();
    const int lane = t & 63, w = t >> 6;
    float aq[8], ak[8], av[8];
#pragma unroll
    for (int j = 0; j < 8; ++j) { aq[j] = bq[lane]; ak[j] = 0.f; av[j] = 0.f; }
#pragma unroll 8
    for (int d = 0; d < 64; ++d) {
        const float wq = Wq[d * 64 + lane];
        const float wk = Wk[(96 + d) * 64 + lane];
        const float wv = Wvo[d * 64 + lane];
#pragma unroll
        for (int j = 0; j < 8; ++j) {
            const float s = se_s[w * 8 + j][d];   // uniform addr -> broadcast
            aq[j] = fmaf(s, wq, aq[j]);
            ak[j] = fmaf(s, wk, ak[j]);
            av[j] = fmaf(s, wv, av[j]);
        }
    }
#pragma unroll
    for (int j = 0; j < 8; ++j) {
        const int v = vbase + w * 8 + j;
        Q[v * 64 + lane]  = aq[j];
        Km[v * 64 + lane] = ak[j];
        VW[v * 64 + lane] = av[j];
    }
}

// ---------------------------------------------------------------------------
// attn6: block = 1024 threads (16 waves) = 2x2x2 voxel tile; 2 WAVES PER
// VOXEL split by p-half (lo: p=0..63, hi: p=64..124). Grid 1000.
// XCD-AWARE CUBIC CHUNKING (proven r6: FETCH 183MB->4.8MB).
// LDS: one union buffer u[216][65] staged twice (Km, then VW reusing it);
// stride 65 -> conflict-free lane-varying reads. OOB rows zero-filled
// (= reference zero padding). Scores kept in registers (shfl broadcast).
// Cross-wave softmax/output combine via tiny LDS arrays. 4 barriers.
// REFERENCE QUIRKS: gather coord = (x+e4-2, y+e3-2, z+e5-2) [x/y digit swap];
// mask coord = (x+e3-2, y+e4-2, z+e5-2) in [1,19]^3; masked score exactly 0.
// ---------------------------------------------------------------------------
__global__ __launch_bounds__(1024, 2) void attn6(
        const float* __restrict__ Q, const float* __restrict__ Km,
        const float* __restrict__ VW,
        const float* __restrict__ k_rel, const float* __restrict__ vrelW,
        const float* __restrict__ bo,
        float* __restrict__ out) {
    __shared__ float u[216 * 65];      // 56.2 KB union buffer (Km, then VW)
    __shared__ float mred[16], sred[16];
    __shared__ float prw[8][64];

    const int tid  = threadIdx.x;
    const int lane = tid & 63;
    const int w    = tid >> 6;         // 0..15
    const int vox  = w & 7;            // voxel within 2x2x2 tile
    const int hi   = w >> 3;           // p-half

    // ---- XCD-aware cubic chunking ----
    const int chunk = blockIdx.x & 7;          // hw XCD (round-robin)
    const int idx   = blockIdx.x >> 3;         // 0..124 within chunk
    const int cx = chunk >> 2, cy = (chunk >> 1) & 1, cz = chunk & 1;
    const int TX = cx * 5 + idx / 25;
    const int TY = cy * 5 + (idx / 5) % 5;
    const int TZ = cz * 5 + idx % 5;

    const int wx = vox >> 2, wy = (vox >> 1) & 1, wz = vox & 1;
    const int x = TX * 2 + wx, y = TY * 2 + wy, z = TZ * 2 + wz;
    const int v = (x * NN + y) * NN + z;

    // ---- stage Km union (216 rows, zero-fill OOB) ----
    for (int i = tid; i < 216 * 16; i += 1024) {
        const int row = i >> 4, ch = i & 15;
        const int ux = row / 36, uy = (row / 6) % 6, uz = row % 6;
        const int gX = TX * 2 - 2 + ux;
        const int gY = TY * 2 - 2 + uy;
        const int gZ = TZ * 2 - 2 + uz;
        float4 val = make_float4(0.f, 0.f, 0.f, 0.f);
        if ((unsigned)gX <= 19u && (unsigned)gY <= 19u && (unsigned)gZ <= 19u)
            val = ((const float4*)Km)[((gX * NN + gY) * NN + gZ) * 16 + ch];
        const int b = row * 65 + ch * 4;
        u[b] = val.x; u[b + 1] = val.y; u[b + 2] = val.z; u[b + 3] = val.w;
    }

    const float q = Q[v * 64 + lane];

    // geometry for this wave's p (digit-swap quirk)
    const int p  = lane + hi * 64;
    const int pc = (p < NP) ? p : (NP - 1);
    const int e3 = pc / 25, e4 = (pc / 5) % 5, e5 = pc % 5;
    const int rowp = 36 * (wx + e4) + 6 * (wy + e3) + (wz + e5);
    const bool mv = (p < NP) &&
                    ((unsigned)(x + e3 - 3) <= 18u) &&
                    ((unsigned)(y + e4 - 3) <= 18u) &&
                    ((unsigned)(z + e5 - 3) <= 18u);
    const float4* __restrict__ kr = (const float4*)(k_rel + pc * 64);

    __syncthreads();   // Km union staged

    // ---- logits: one p per lane ----
    float a = 0.f;
#pragma unroll
    for (int i = 0; i < 16; ++i) {
        const float qa = __shfl(q, 4 * i + 0);
        const float qb = __shfl(q, 4 * i + 1);
        const float qc = __shfl(q, 4 * i + 2);
        const float qd = __shfl(q, 4 * i + 3);
        const float4 r = kr[i];
        const int b = rowp * 65 + 4 * i;
        a = fmaf(u[b]     + r.x, qa, a);
        a = fmaf(u[b + 1] + r.y, qb, a);
        a = fmaf(u[b + 2] + r.z, qc, a);
        a = fmaf(u[b + 3] + r.w, qd, a);
    }
    const float l = mv ? a : -1e9f;

    // wave-local max
    float m = l;
#pragma unroll
    for (int d = 1; d < 64; d <<= 1) m = fmaxf(m, __shfl_xor(m, d));
    if (lane == 0) mred[w] = m;
    __syncthreads();   // mred ready; all u(Km) reads done -> u reusable

    // ---- stage VW union (overwrites u), overlapped with softmax combine ----
    for (int i = tid; i < 216 * 16; i += 1024) {
        const int row = i >> 4, ch = i & 15;
        const int ux = row / 36, uy = (row / 6) % 6, uz = row % 6;
        const int gX = TX * 2 - 2 + ux;
        const int gY = TY * 2 - 2 + uy;
        const int gZ = TZ * 2 - 2 + uz;
        float4 val = make_float4(0.f, 0.f, 0.f, 0.f);
        if ((unsigned)gX <= 19u && (unsigned)gY <= 19u && (unsigned)gZ <= 19u)
            val = ((const float4*)VW)[((gX * NN + gY) * NN + gZ) * 16 + ch];
        const int b = row * 65 + ch * 4;
        u[b] = val.x; u[b + 1] = val.y; u[b + 2] = val.z; u[b + 3] = val.w;
    }

    const float mm = fmaxf(mred[vox], mred[vox + 8]);
    const float e  = __expf(l - mm);          // masked / clamped lanes -> 0
    float s = e;
#pragma unroll
    for (int d = 1; d < 64; d <<= 1) s += __shfl_xor(s, d);
    if (lane == 0) sred[w] = s;
    __syncthreads();   // sred ready + u(VW) staged

    const float inv = 1.f / (sred[vox] + sred[vox + 8]);
    const float sc_mine = e * inv;     // this lane's score for its p

    // ---- weighted sum: lane = channel; each wave its own p-half ----
    float A0 = 0.f, A1 = 0.f, A2 = 0.f, A3 = 0.f, A4 = 0.f;
    const float* __restrict__ vr = vrelW + lane;
    if (hi == 0) {
#pragma unroll
        for (int pp = 0; pp < 64; ++pp) {
            const int f3 = pp / 25, f4 = (pp / 5) % 5, f5 = pp % 5;
            const int row = 36 * (wx + f4) + 6 * (wy + f3) + (wz + f5);
            const float sc = __shfl(sc_mine, pp);
            float& A = (pp % 5 == 0) ? A0 : (pp % 5 == 1) ? A1 :
                       (pp % 5 == 2) ? A2 : (pp % 5 == 3) ? A3 : A4;
            A = fmaf(sc, u[row * 65 + lane] + vr[pp * 64], A);
        }
    } else {
#pragma unroll
        for (int pp = 64; pp < NP; ++pp) {
            const int f3 = pp / 25, f4 = (pp / 5) % 5, f5 = pp % 5;
            const int row = 36 * (wx + f4) + 6 * (wy + f3) + (wz + f5);
            const float sc = __shfl(sc_mine, pp - 64);
            float& A = (pp % 5 == 0) ? A0 : (pp % 5 == 1) ? A1 :
                       (pp % 5 == 2) ? A2 : (pp % 5 == 3) ? A3 : A4;
            A = fmaf(sc, u[row * 65 + lane] + vr[pp * 64], A);
        }
    }
    const float part = ((A0 + A1) + (A2 + A3)) + A4;
    if (hi == 1) prw[vox][lane] = part;
    __syncthreads();
    if (hi == 0)
        out[v * 64 + lane] = part + prw[vox][lane] + bo[lane];
}

// ---------------------------------------------------------------------------
extern "C" void kernel_launch(void* const* d_in, const int* in_sizes, int n_in,
                              void* d_out, int out_size, void* d_ws, size_t ws_size,
                              hipStream_t stream) {
    const float* SE  = (const float*)d_in[0];
    const float* rpw = (const float*)d_in[1];
    const float* Wq  = (const float*)d_in[2];
    const float* bq  = (const float*)d_in[3];
    const float* Wk  = (const float*)d_in[4];
    const float* bk  = (const float*)d_in[5];
    const float* Wv  = (const float*)d_in[6];
    const float* bv  = (const float*)d_in[7];
    const float* Wo  = (const float*)d_in[8];
    const float* bo  = (const float*)d_in[9];
    float* out = (float*)d_out;

    float* ws    = (float*)d_ws;
    float* Q     = ws;                 // 8000*64
    float* Km    = ws + 512000;        // 8000*64
    float* VW    = ws + 1024000;       // 8000*64
    float* k_rel = ws + 1536000;       // 125*64
    float* vrelW = ws + 1544000;       // 125*64
    float* Wvo   = ws + 1552000;       // 64*64

    prep<<<NP + 64, 64, 0, stream>>>(rpw, Wk, bk, Wv, bv, Wo, k_rel, vrelW, Wvo);
    qkv2<<<NV / 32, 256, 0, stream>>>(SE, Wq, bq, Wk, Wvo, Q, Km, VW);
    attn6<<<1000, 1024, 0, stream>>>(Q, Km, VW, k_rel, vrelW, bo, out);
}

// Round 9
// 137.552 us; speedup vs baseline: 1.1034x; 1.0811x over previous
//
#include <hip/hip_runtime.h>

#define NN 20
#define NP 125          // 5^3 window
#define NV (NN*NN*NN)   // 8000

__device__ __forceinline__ float rlf(float v, int l) {
    return __uint_as_float(__builtin_amdgcn_readlane(__float_as_uint(v), l));
}

// ---------------------------------------------------------------------------
// prep: blocks 0..124  -> k_rel[p][c]  = bk + relpos_flat[p] @ Wk[0:96]
//                         vrelW[p][c]  = (bv + relpos_flat[p] @ Wv[0:96]) @ Wo
//       blocks 125..188 -> Wvo[d][c]   = Wv[96+d][:] @ Wo     (64x64)
// ---------------------------------------------------------------------------
__global__ __launch_bounds__(64) void prep(
        const float* __restrict__ rpw,
        const float* __restrict__ Wk, const float* __restrict__ bk,
        const float* __restrict__ Wv, const float* __restrict__ bv,
        const float* __restrict__ Wo,
        float* __restrict__ k_rel, float* __restrict__ vrelW,
        float* __restrict__ Wvo) {
    const int c = threadIdx.x;
    if (blockIdx.x < NP) {
        const int p = blockIdx.x;
        const int d3 = p / 25, d4 = (p / 5) % 5, d5 = p % 5;
        __shared__ float vtmp[64];
        float ak = bk[c], av = bv[c];
#pragma unroll
        for (int t = 0; t < 96; ++t) {
            const int blk = t >> 5, off = t & 31;
            const int row = (blk == 0) ? d3 : (blk == 1) ? d4 : d5;
            const float r = rpw[row * 32 + off];
            ak = fmaf(r, Wk[t * 64 + c], ak);
            av = fmaf(r, Wv[t * 64 + c], av);
        }
        k_rel[p * 64 + c] = ak;
        vtmp[c] = av;
        __syncthreads();
        float o = 0.f;
#pragma unroll 8
        for (int e = 0; e < 64; ++e)
            o = fmaf(vtmp[e], Wo[e * 64 + c], o);
        vrelW[p * 64 + c] = o;
    } else {
        const int d = blockIdx.x - NP;
        float acc = 0.f;
#pragma unroll 8
        for (int e = 0; e < 64; ++e)
            acc = fmaf(Wv[(96 + d) * 64 + e], Wo[e * 64 + c], acc);
        Wvo[d * 64 + c] = acc;
    }
}

// ---------------------------------------------------------------------------
// qkv3: Q = SE@Wq + bq ; Km = SE@Wk[96:] ; VW = SE@Wvo ; qkr[v][p] = Q[v].k_rel[p]
// 250 blocks x 256 threads, 32 voxels/block (8 per wave).
// k_rel staged once in LDS (stride 65: bank=(lane+4i)%32, 2-way free) and
// amortized over 32 voxels -> removes the per-row k_rel gather from attn.
// ---------------------------------------------------------------------------
__global__ __launch_bounds__(256) void qkv3(
        const float* __restrict__ SE,
        const float* __restrict__ Wq, const float* __restrict__ bq,
        const float* __restrict__ Wk, const float* __restrict__ Wvo,
        const float* __restrict__ k_rel,
        float* __restrict__ Q, float* __restrict__ Km, float* __restrict__ VW,
        float* __restrict__ qkr) {
    __shared__ float se_s[32][65];
    __shared__ float krs[125 * 65];
    const int t = threadIdx.x;
    const int vbase = blockIdx.x * 32;
    {   // stage 32x64 SE floats = 512 float4, 2 per thread
        const float4* __restrict__ src = (const float4*)(SE + vbase * 64);
        const float4 a = src[t];
        const float4 b = src[t + 256];
        const int r0 = t >> 4,        c0 = (t & 15) * 4;
        const int r1 = (t + 256) >> 4;
        se_s[r0][c0 + 0] = a.x; se_s[r0][c0 + 1] = a.y;
        se_s[r0][c0 + 2] = a.z; se_s[r0][c0 + 3] = a.w;
        se_s[r1][c0 + 0] = b.x; se_s[r1][c0 + 1] = b.y;
        se_s[r1][c0 + 2] = b.z; se_s[r1][c0 + 3] = b.w;
    }
    // stage k_rel 125x64 into LDS (stride 65)
    for (int i = t; i < 125 * 16; i += 256) {
        const int row = i >> 4, ch = i & 15;
        const float4 val = ((const float4*)k_rel)[row * 16 + ch];
        const int b = row * 65 + ch * 4;
        krs[b] = val.x; krs[b + 1] = val.y; krs[b + 2] = val.z; krs[b + 3] = val.w;
    }
    __syncthreads();
    const int lane = t & 63, w = t >> 6;
    float aq[8], ak[8], av[8];
#pragma unroll
    for (int j = 0; j < 8; ++j) { aq[j] = bq[lane]; ak[j] = 0.f; av[j] = 0.f; }
#pragma unroll 8
    for (int d = 0; d < 64; ++d) {
        const float wq = Wq[d * 64 + lane];
        const float wk = Wk[(96 + d) * 64 + lane];
        const float wv = Wvo[d * 64 + lane];
#pragma unroll
        for (int j = 0; j < 8; ++j) {
            const float s = se_s[w * 8 + j][d];   // uniform addr -> broadcast
            aq[j] = fmaf(s, wq, aq[j]);
            ak[j] = fmaf(s, wk, ak[j]);
            av[j] = fmaf(s, wv, av[j]);
        }
    }
#pragma unroll
    for (int j = 0; j < 8; ++j) {
        const int v = vbase + w * 8 + j;
        Q[v * 64 + lane]  = aq[j];
        Km[v * 64 + lane] = ak[j];
        VW[v * 64 + lane] = av[j];
    }
    // qkr: lane = p (2 p's per lane), q broadcast via readlane (VALU)
    const int p1c = (lane + 64 < NP) ? (lane + 64) : (NP - 1);
#pragma unroll
    for (int j = 0; j < 8; ++j) {
        float d0 = 0.f, d1 = 0.f;
#pragma unroll
        for (int i = 0; i < 16; ++i) {
            const float qa = rlf(aq[j], 4 * i + 0);
            const float qb = rlf(aq[j], 4 * i + 1);
            const float qc = rlf(aq[j], 4 * i + 2);
            const float qd = rlf(aq[j], 4 * i + 3);
            const int b0 = lane * 65 + 4 * i;
            const int b1 = p1c * 65 + 4 * i;
            d0 = fmaf(krs[b0], qa, d0); d0 = fmaf(krs[b0 + 1], qb, d0);
            d0 = fmaf(krs[b0 + 2], qc, d0); d0 = fmaf(krs[b0 + 3], qd, d0);
            d1 = fmaf(krs[b1], qa, d1); d1 = fmaf(krs[b1 + 1], qb, d1);
            d1 = fmaf(krs[b1 + 2], qc, d1); d1 = fmaf(krs[b1 + 3], qd, d1);
        }
        const int v = vbase + w * 8 + j;
        qkr[v * 128 + lane] = d0;
        qkr[v * 128 + 64 + lane] = d1;   // slots >=125 never read
    }
}

// ---------------------------------------------------------------------------
// attn7: block = 512 thr (8 waves) = 2x2x2 tile; grid 1000, XCD cubic chunking
// (r6-proven). DS-pipe minimized:
//  - logits: lane owns union rows lane+64m -> row%32==lane%32; stride 68
//    floats (16B aligned) -> ds_read_b128, exactly 2-way (conflict-free).
//  - q-broadcast + score-broadcast via v_readlane (VALU, not DS).
//  - scores stay in registers; 8-bpermute redistribution puts score(p) at
//    lane p so the weighted sum uses literal readlane.
//  - k_rel folded in via precomputed qkr scalar (1 gather vs 16 float4).
// REFERENCE QUIRKS: gather coord = (x+e4-2, y+e3-2, z+e5-2) [x/y digit swap];
// mask coord = (x+e3-2, y+e4-2, z+e5-2) in [1,19]^3; masked score exactly 0;
// OOB gather rows zero-filled at staging (= reference zero padding).
// ---------------------------------------------------------------------------
__global__ __launch_bounds__(512, 2) void attn7(
        const float* __restrict__ Q, const float* __restrict__ Km,
        const float* __restrict__ VW, const float* __restrict__ qkr,
        const float* __restrict__ vrelW, const float* __restrict__ bo,
        float* __restrict__ out) {
    __shared__ __align__(16) float u[216 * 68];   // 58.75 KB union buffer

    const int tid  = threadIdx.x;
    const int lane = tid & 63;
    const int w    = tid >> 6;

    // ---- XCD-aware cubic chunking ----
    const int chunk = blockIdx.x & 7;
    const int idx   = blockIdx.x >> 3;
    const int cx = chunk >> 2, cy = (chunk >> 1) & 1, cz = chunk & 1;
    const int TX = cx * 5 + idx / 25;
    const int TY = cy * 5 + (idx / 5) % 5;
    const int TZ = cz * 5 + idx % 5;

    const int wx = w >> 2, wy = (w >> 1) & 1, wz = w & 1;
    const int x = TX * 2 + wx, y = TY * 2 + wy, z = TZ * 2 + wz;
    const int v = (x * NN + y) * NN + z;

    // ---- stage Km union (216 rows, zero-fill OOB) with ds_write_b128 ----
    for (int i = tid; i < 216 * 16; i += 512) {
        const int row = i >> 4, ch = i & 15;
        const int ux = row / 36, uy = (row / 6) % 6, uz = row % 6;
        const int gX = TX * 2 - 2 + ux;
        const int gY = TY * 2 - 2 + uy;
        const int gZ = TZ * 2 - 2 + uz;
        float4 val = make_float4(0.f, 0.f, 0.f, 0.f);
        if ((unsigned)gX <= 19u && (unsigned)gY <= 19u && (unsigned)gZ <= 19u)
            val = ((const float4*)Km)[((gX * NN + gY) * NN + gZ) * 16 + ch];
        *(float4*)&u[row * 68 + ch * 4] = val;
    }

    const float q = Q[v * 64 + lane];

    // ---- per-lane union rows: r_m = lane + 64m ----
    int   rr0, rr1, rr2, rr3;
    float qk0, qk1, qk2, qk3;
    bool  vd0, vd1, vd2, vd3;
#define GEO(M, RR, QK, VD)                                                     \
    {                                                                          \
        const int r = lane + 64 * (M);                                         \
        const bool okr = (r < 216);                                            \
        const int rc = okr ? r : 0;                                            \
        const int ux = rc / 36, uy = (rc / 6) % 6, uz = rc % 6;                \
        const int E4 = ux - wx, E3 = uy - wy, E5 = uz - wz;                    \
        const bool win = okr && (unsigned)E3 <= 4u && (unsigned)E4 <= 4u &&    \
                         (unsigned)E5 <= 4u;                                   \
        const bool mv = win && (unsigned)(x + E3 - 3) <= 18u &&                \
                        (unsigned)(y + E4 - 3) <= 18u &&                       \
                        (unsigned)(z + E5 - 3) <= 18u;                         \
        const int p = 25 * E3 + 5 * E4 + E5;                                   \
        RR = rc; VD = mv;                                                      \
        QK = qkr[v * 128 + (mv ? p : 0)];                                      \
    }
    GEO(0, rr0, qk0, vd0)
    GEO(1, rr1, qk1, vd1)
    GEO(2, rr2, qk2, vd2)
    GEO(3, rr3, qk3, vd3)
#undef GEO

    __syncthreads();   // Km union staged

    // ---- logits: conflict-free b128 reads + readlane q ----
    float a0 = 0.f, a1 = 0.f, a2 = 0.f, a3 = 0.f;
#pragma unroll
    for (int i = 0; i < 16; ++i) {
        const float qa = rlf(q, 4 * i + 0);
        const float qb = rlf(q, 4 * i + 1);
        const float qc = rlf(q, 4 * i + 2);
        const float qd = rlf(q, 4 * i + 3);
        const float4 k0 = *(const float4*)&u[rr0 * 68 + 4 * i];
        const float4 k1 = *(const float4*)&u[rr1 * 68 + 4 * i];
        const float4 k2 = *(const float4*)&u[rr2 * 68 + 4 * i];
        const float4 k3 = *(const float4*)&u[rr3 * 68 + 4 * i];
        a0 = fmaf(k0.x, qa, a0); a0 = fmaf(k0.y, qb, a0);
        a0 = fmaf(k0.z, qc, a0); a0 = fmaf(k0.w, qd, a0);
        a1 = fmaf(k1.x, qa, a1); a1 = fmaf(k1.y, qb, a1);
        a1 = fmaf(k1.z, qc, a1); a1 = fmaf(k1.w, qd, a1);
        a2 = fmaf(k2.x, qa, a2); a2 = fmaf(k2.y, qb, a2);
        a2 = fmaf(k2.z, qc, a2); a2 = fmaf(k2.w, qd, a2);
        a3 = fmaf(k3.x, qa, a3); a3 = fmaf(k3.y, qb, a3);
        a3 = fmaf(k3.z, qc, a3); a3 = fmaf(k3.w, qd, a3);
    }
    const float l0 = vd0 ? a0 + qk0 : -1e9f;
    const float l1 = vd1 ? a1 + qk1 : -1e9f;
    const float l2 = vd2 ? a2 + qk2 : -1e9f;
    const float l3 = vd3 ? a3 + qk3 : -1e9f;

    // ---- softmax over the 216 union slots (invalid = -1e9 -> exp 0) ----
    float mm = fmaxf(fmaxf(l0, l1), fmaxf(l2, l3));
#pragma unroll
    for (int d = 1; d < 64; d <<= 1) mm = fmaxf(mm, __shfl_xor(mm, d));
    const float e0 = __expf(l0 - mm);
    const float e1 = __expf(l1 - mm);
    const float e2 = __expf(l2 - mm);
    const float e3v = __expf(l3 - mm);
    float ss = ((e0 + e1) + (e2 + e3v));
#pragma unroll
    for (int d = 1; d < 64; d <<= 1) ss += __shfl_xor(ss, d);
    const float inv = 1.f / ss;
    const float sA = e0 * inv, sB = e1 * inv, sC = e2 * inv, sD = e3v * inv;

    // ---- redistribute: score of p -> lane p (regs s0: p=lane, s1: p=64+lane)
    int d3 = lane / 25, d4 = (lane / 5) % 5, d5 = lane % 5;
    const int r0 = 36 * (wx + d4) + 6 * (wy + d3) + (wz + d5);
    const int p1c = (lane + 64 < NP) ? (lane + 64) : (NP - 1);
    d3 = p1c / 25; d4 = (p1c / 5) % 5; d5 = p1c % 5;
    const int r1 = 36 * (wx + d4) + 6 * (wy + d3) + (wz + d5);
    const float cA0 = __shfl(sA, r0 & 63), cB0 = __shfl(sB, r0 & 63);
    const float cC0 = __shfl(sC, r0 & 63), cD0 = __shfl(sD, r0 & 63);
    const int sl0 = r0 >> 6;
    const float s0 = (sl0 == 0) ? cA0 : (sl0 == 1) ? cB0 : (sl0 == 2) ? cC0 : cD0;
    const float cA1 = __shfl(sA, r1 & 63), cB1 = __shfl(sB, r1 & 63);
    const float cC1 = __shfl(sC, r1 & 63), cD1 = __shfl(sD, r1 & 63);
    const int sl1 = r1 >> 6;
    const float s1 = (sl1 == 0) ? cA1 : (sl1 == 1) ? cB1 : (sl1 == 2) ? cC1 : cD1;

    __syncthreads();   // all u(Km) reads done -> u reusable

    // ---- stage VW union (reuses u) ----
    for (int i = tid; i < 216 * 16; i += 512) {
        const int row = i >> 4, ch = i & 15;
        const int ux = row / 36, uy = (row / 6) % 6, uz = row % 6;
        const int gX = TX * 2 - 2 + ux;
        const int gY = TY * 2 - 2 + uy;
        const int gZ = TZ * 2 - 2 + uz;
        float4 val = make_float4(0.f, 0.f, 0.f, 0.f);
        if ((unsigned)gX <= 19u && (unsigned)gY <= 19u && (unsigned)gZ <= 19u)
            val = ((const float4*)VW)[((gX * NN + gY) * NN + gZ) * 16 + ch];
        *(float4*)&u[row * 68 + ch * 4] = val;
    }
    __syncthreads();

    // ---- weighted sum: lane = channel; scores via literal readlane ----
    float A0 = 0.f, A1 = 0.f, A2 = 0.f, A3 = 0.f, A4 = 0.f;
    const float* __restrict__ vr = vrelW + lane;
#pragma unroll 5
    for (int g = 0; g < 25; ++g) {
        const int ge3 = g / 5, ge4 = g % 5;
        const int rb = 36 * (wx + ge4) + 6 * (wy + ge3) + wz;
        const int pb = g * 5;
#define STEP(J, ACC)                                                           \
        {                                                                      \
            const int p = pb + (J);                                            \
            const float sc = (p < 64) ? rlf(s0, p) : rlf(s1, p - 64);          \
            ACC = fmaf(sc, u[(rb + (J)) * 68 + lane] + vr[p * 64], ACC);       \
        }
        STEP(0, A0) STEP(1, A1) STEP(2, A2) STEP(3, A3) STEP(4, A4)
#undef STEP
    }
    const float rw = ((A0 + A1) + (A2 + A3)) + A4;
    out[v * 64 + lane] = rw + bo[lane];
}

// ---------------------------------------------------------------------------
extern "C" void kernel_launch(void* const* d_in, const int* in_sizes, int n_in,
                              void* d_out, int out_size, void* d_ws, size_t ws_size,
                              hipStream_t stream) {
    const float* SE  = (const float*)d_in[0];
    const float* rpw = (const float*)d_in[1];
    const float* Wq  = (const float*)d_in[2];
    const float* bq  = (const float*)d_in[3];
    const float* Wk  = (const float*)d_in[4];
    const float* bk  = (const float*)d_in[5];
    const float* Wv  = (const float*)d_in[6];
    const float* bv  = (const float*)d_in[7];
    const float* Wo  = (const float*)d_in[8];
    const float* bo  = (const float*)d_in[9];
    float* out = (float*)d_out;

    float* ws    = (float*)d_ws;
    float* Q     = ws;                 // 8000*64
    float* Km    = ws + 512000;        // 8000*64
    float* VW    = ws + 1024000;       // 8000*64
    float* k_rel = ws + 1536000;       // 125*64
    float* vrelW = ws + 1544000;       // 125*64
    float* Wvo   = ws + 1552000;       // 64*64
    float* qkr   = ws + 1556096;       // 8000*128

    prep<<<NP + 64, 64, 0, stream>>>(rpw, Wk, bk, Wv, bv, Wo, k_rel, vrelW, Wvo);
    qkv3<<<NV / 32, 256, 0, stream>>>(SE, Wq, bq, Wk, Wvo, k_rel, Q, Km, VW, qkr);
    attn7<<<1000, 512, 0, stream>>>(Q, Km, VW, qkr, vrelW, bo, out);
}